// Round 16
// baseline (114.203 us; speedup 1.0000x reference)
//
#include <hip/hip_runtime.h>
#include <hip/hip_bf16.h>

#define CC 64
#define HH 128
#define WW 128
#define OO 576   // C * K * K
#define HW (HH * WW)

typedef __attribute__((ext_vector_type(8))) short short8;
typedef __attribute__((ext_vector_type(4))) short short4v;
typedef __attribute__((ext_vector_type(4))) float floatx4;
typedef __attribute__((ext_vector_type(4))) unsigned int uint4v;

__device__ __forceinline__ unsigned short f2bf(float f) {
    unsigned u = __float_as_uint(f);
    u = (u + 0x7FFFu + ((u >> 16) & 1u)) >> 16;   // RTNE
    return (unsigned short)u;
}

__device__ __forceinline__ float bf2f(short s) {
    return __uint_as_float(((unsigned)(unsigned short)s) << 16);
}

// Pre-kernel, 3 jobs in one grid:
//   blocks [0,1024): x (f32, [b][c][h][w]) -> xbf (bf16, [b][h][w][c])
//     via LDS-tiled transpose: reads coalesced along w, writes coalesced
//     along c. x is read ONCE, linearly (HBM-optimal), so the main kernel
//     never touches the f32 gather pattern that dominated its staging.
//   blocks [1024,1168): W_gen -> bf16 tap-major Wb; bias -> tap-major Bp.
__global__ __launch_bounds__(256) void ACDA_pre_kernel(
    const float* __restrict__ x, const float* __restrict__ Wg,
    const float* __restrict__ bg, unsigned short* __restrict__ Wb,
    float* __restrict__ Bp, unsigned short* __restrict__ xbf)
{
    const int bid = blockIdx.x, tid = threadIdx.x;
    if (bid >= 1024) {
        int i = (bid - 1024) * 256 + tid;
        if (i < OO * CC) {
            int o2  = i >> 6;
            int col = i & 63;
            int kk  = o2 >> 6;
            int c   = o2 & 63;
            Wb[i] = f2bf(Wg[(c * 9 + kk) * CC + col]);
        }
        if (i < OO) Bp[i] = bg[(i & 63) * 9 + (i >> 6)];
        return;
    }
    // transpose tile: one (b, h) row-plane, 64 ch x 128 w
    const int b = bid >> 7, h = bid & 127;
    __shared__ float T[64][132];   // pad 128->132 (16B-aligned rows)

    {   // IN: thread (c = tid>>2, q = tid&3): 8x dwordx4 along w
        const int c = tid >> 2, q = tid & 3;
        const float* sp = x + ((size_t)(b * CC + c) * HH + h) * WW + q * 32;
#pragma unroll
        for (int j = 0; j < 8; ++j)
            *(floatx4*)&T[c][q * 32 + 4 * j] = *(const floatx4*)(sp + 4 * j);
    }
    __syncthreads();
    {   // OUT: thread (w = tid>>1, half = tid&1): 32 LDS reads -> 16
        // cvt_pk -> 64B coalesced store of channels half*32..+31
        const int w = tid >> 1, half = tid & 1;
        unsigned u[16];
#pragma unroll
        for (int k = 0; k < 16; ++k) {
            float f0 = T[half * 32 + 2 * k][w];
            float f1 = T[half * 32 + 2 * k + 1][w];
            __hip_bfloat162 p = __float22bfloat162_rn(make_float2(f0, f1));
            __builtin_memcpy(&u[k], &p, 4);
        }
        unsigned short* dp = xbf + ((size_t)(b * HH + h) * WW + w) * CC + half * 32;
#pragma unroll
        for (int m = 0; m < 4; ++m) {
            uint4v v = {u[4 * m], u[4 * m + 1], u[4 * m + 2], u[4 * m + 3]};
            *(uint4v*)(dp + m * 8) = v;
        }
    }
}

// R15 post-mortem: bfrag pin neutral; main pinned at ~40us with all pipes
// idle and occupancy-independence proven. Last uncosted phase: STAGING --
// one generation means all 8192 waves burst 64MB of 256B/64KB-stride
// gathers at once (HBM row-thrash on the 17MB cold fetch + barrier on the
// slowest straggler + pack8 VALU). This round: staging reads the
// channel-inner bf16 xbf instead -- ~4.6 coalesced dwordx4 + ~4.6
// contiguous ds_write_b128 per thread (bank-minimal), zero packing VALU,
// halo pass deleted, cold bytes halved. Slab contents bit-identical.
__global__ __launch_bounds__(512, 4) void ACDA_main_kernel(
    const unsigned short* __restrict__ xbf, const unsigned short* __restrict__ Wb,
    const float* __restrict__ Bp, float* __restrict__ out)
{
    // S[r][s][c]: r = slab row (x row h0+r-1; zeroed if OOB), s = col slot
    // (0 = left halo, 1..64 = w0..w0+63, 65 = right halo; zeroed at edge),
    // c = channel, padded 64->72 (row stride 144B = 9x16B).
    __shared__ short S[4][66][72];   // 38016 B -> 4 blocks/CU

    const int tid  = threadIdx.x;
    const int lane = tid & 63;
    const int g    = tid >> 6;       // wave 0..7
    const int hw   = g & 1;          // which of the 2 h-rows
    const int cg   = g >> 1;         // 16-channel group 0..3
    const int quad = lane >> 4;
    const int l16  = lane & 15;
    const int c0   = cg * 16;

    // Bijective XCD swizzle: 1024 blocks, 128/XCD = one image per XCD.
    const int bid = blockIdx.x;
    const int wk  = (bid & 7) * 128 + (bid >> 3);
    const int seg = wk & 1;
    const int hp  = (wk >> 1) & 63;
    const int b   = wk >> 7;
    const int w0  = seg << 6;
    const int h0  = hp << 1;         // this block: output rows h0, h0+1

    const unsigned short* xq = xbf + (size_t)b * (HH * WW * CC);

    // ---- slab staging from xbf: 2112 16B-chunks, lane-consecutive ----
    // chunk c16: slot = c16>>3 (r = slot/66, s = slot%66), ch8 = c16&7.
    // Global: consecutive lanes -> consecutive 16B (perfect coalescing).
    // LDS: consecutive lanes -> consecutive 16B (bank-minimal b128).
#define STAGE_CHUNK(C16) do {                                               \
        const int slot_ = (C16) >> 3, ch8_ = (C16) & 7;                     \
        const int r_ = slot_ / 66;                                          \
        const int s_ = slot_ - 66 * r_;                                     \
        const int hh_ = h0 + r_ - 1;                                        \
        const int w_  = w0 + s_ - 1;                                        \
        short8 v_ = {0, 0, 0, 0, 0, 0, 0, 0};                               \
        if ((unsigned)hh_ < 128u && (unsigned)w_ < 128u)                    \
            v_ = *(const short8*)(xq + ((size_t)hh_ * WW + w_) * CC + ch8_ * 8); \
        *(short8*)((char*)&S[0][0][0] + slot_ * 144 + ch8_ * 16) = v_;      \
    } while (0)

#pragma unroll
    for (int j = 0; j < 4; ++j) STAGE_CHUNK(tid + j * 512);
    if (tid < 64) STAGE_CHUNK(2048 + tid);
#undef STAGE_CHUNK

    __syncthreads();   // the ONLY barrier; S read-only afterwards

    // ---- B fragments: direct short8 ds_read from slab row hw+1, pinned
    // in VGPRs (origin made opaque -> no LDS rematerialization).
    short8 bfrag[4][2];
#pragma unroll
    for (int nt = 0; nt < 4; ++nt)
#pragma unroll
        for (int ks = 0; ks < 2; ++ks) {
            bfrag[nt][ks] = *(const short8*)&S[hw + 1][nt * 16 + l16 + 1][ks * 32 + quad * 8];
            asm volatile("" : "+v"(bfrag[nt][ks]));
        }

    // Output accumulator in MFMA layout: acc[nt][rg] <-> channel
    // c0+4*quad+rg, pixel (h0+hw, w0+16*nt+l16).
    floatx4 acc[4];
#pragma unroll
    for (int nt = 0; nt < 4; ++nt) acc[nt] = floatx4{0.f, 0.f, 0.f, 0.f};

    // ---- 9 taps, fully unrolled. Per tap: A 2xb128 + bias b128 (L2-hot);
    // 4x ds_read_b64 patches; 8 MFMA (bias as acc-init); 16 relu-FMA.
#pragma unroll
    for (int t = 0; t < 9; ++t) {
        const int di = t / 3;
        const int dj = t - 3 * di;
        const unsigned short* wrow = Wb + (t * 64 + c0 + l16) * CC + quad * 8;
        short8 a0 = *(const short8*)(wrow);
        short8 a1 = *(const short8*)(wrow + 32);
        floatx4 bv = *(const floatx4*)(Bp + t * 64 + c0 + 4 * quad);
#pragma unroll
        for (int nt = 0; nt < 4; ++nt) {
            short4v ph = *(const short4v*)&S[hw + di][nt * 16 + l16 + dj][c0 + 4 * quad];
            floatx4 z = bv;   // bias pre-ReLU as accumulator init
            z = __builtin_amdgcn_mfma_f32_16x16x32_bf16(a0, bfrag[nt][0], z, 0, 0, 0);
            z = __builtin_amdgcn_mfma_f32_16x16x32_bf16(a1, bfrag[nt][1], z, 0, 0, 0);
#pragma unroll
            for (int rg = 0; rg < 4; ++rg)
                acc[nt][rg] = fmaf(fmaxf(z[rg], 0.f), bf2f(ph[rg]), acc[nt][rg]);
        }
    }

    // ---- epilogue: stores directly from MFMA-layout acc ----
    float* ob = out + (size_t)b * CC * HW + (h0 + hw) * WW + w0;
#pragma unroll
    for (int nt = 0; nt < 4; ++nt)
#pragma unroll
        for (int rg = 0; rg < 4; ++rg)
            ob[(c0 + 4 * quad + rg) * HW + nt * 16 + l16] = acc[nt][rg];
}

extern "C" void kernel_launch(void* const* d_in, const int* in_sizes, int n_in,
                              void* d_out, int out_size, void* d_ws, size_t ws_size,
                              hipStream_t stream) {
    const float* x  = (const float*)d_in[0];
    const float* Wg = (const float*)d_in[1];
    const float* bg = (const float*)d_in[2];
    float* out = (float*)d_out;
    unsigned short* Wb  = (unsigned short*)d_ws;               // 73728 B
    float* Bp           = (float*)((char*)d_ws + OO * CC * 2); // + 2304 B
    unsigned short* xbf = (unsigned short*)((char*)d_ws + 131072); // 16 MiB

    ACDA_pre_kernel<<<dim3(1024 + 144), dim3(256), 0, stream>>>(x, Wg, bg, Wb, Bp, xbf);
    ACDA_main_kernel<<<dim3(8 * 64 * 2), dim3(512), 0, stream>>>(xbf, Wb, Bp, out);
}